// Round 6
// baseline (284.782 us; speedup 1.0000x reference)
//
#include <hip/hip_runtime.h>

typedef unsigned short u16;
typedef unsigned int u32;
typedef _Float16 half8 __attribute__((ext_vector_type(8)));
typedef float f32x4 __attribute__((ext_vector_type(4)));

// Problem constants (verified: fp32 in, fp32 out buffer of 16810016 elems)
#define BT    32768
#define CD    512
#define KC    1024
#define LOFF1 16777216
#define LOFF2 16777232
#define IOFF  16777248

// ws layout (bytes); ws >= 4 MB (probe round 4)
#define WS_EH   0          // u16 ehT[1024*512] fragment-major (1 MB)
#define WS_E2   1048576    // float e2[1024]
#define WS_PART 1052672    // float part[1024]

static __device__ __forceinline__ u16 f2h(float f) {
  union { _Float16 h; u16 u; } c;
  c.h = (_Float16)f;   // RTE, identical rounding to all prior rounds
  return c.u;
}

// ---------------- Kernel 1: emb -> fp16 fragment-major ehT + exact fp32 e2 ---
// ehT layout (u16 index): ((gt*64 + ks*4 + lq)*16 + lm)*8 + j
//   gt = col>>4 (16-col tile), lm = col&15, k = ks*32 + lq*8 + j.
// A wave's B-fragment load in kernel 2 is then base + lane*16B: one
// contiguous 1 KB segment.
__global__ __launch_bounds__(256) void conve_kernel(const float* __restrict__ emb,
                                                    u16* __restrict__ eh,
                                                    float* __restrict__ e2) {
  const int lane = threadIdx.x & 63;
  const int r    = blockIdx.x * 4 + (threadIdx.x >> 6);
  const float4* er = reinterpret_cast<const float4*>(emb + (size_t)r * CD);
  const float4 a = er[lane*2], b = er[lane*2+1];
  uint4 o;
  o.x = (u32)f2h(a.x) | ((u32)f2h(a.y) << 16);
  o.y = (u32)f2h(a.z) | ((u32)f2h(a.w) << 16);
  o.z = (u32)f2h(b.x) | ((u32)f2h(b.y) << 16);
  o.w = (u32)f2h(b.z) | ((u32)f2h(b.w) << 16);
  // cols lane*8..+7 -> (ks = lane>>2, lq = lane&3, j = 0..7) exactly
  const int gt = r >> 4, lm = r & 15;
  const int ks = lane >> 2, lq = lane & 3;
  reinterpret_cast<uint4*>(eh)[(gt*64 + ks*4 + lq)*16 + lm] = o;
  float s = a.x*a.x + a.y*a.y + a.z*a.z + a.w*a.w
          + b.x*b.x + b.y*b.y + b.z*b.z + b.w*b.w;
  for (int off = 32; off > 0; off >>= 1) s += __shfl_down(s, off, 64);
  if (lane == 0) e2[r] = s;
}

// ---------------- Kernel 2: fused convert+MFMA+argmin+refine+gather ----------
// Block = 32 rows, 256 threads (4 waves), 1024 blocks, pin = 4 waves/EU.
// Register-budget design (the round-4/5 lesson): under waves_per_eu(4,4) the
// gfx950 allocator splits the 128-reg unified budget 64 arch / 64 AGPR.
// Rounds 4/5: arch live ~81 -> 17-reg spill (WRITE 180 MB). Fix: halve the
// per-wave column fan-out to 2 col-tiles. Arch live: bf 2deep x 2tiles = 16,
// af[2] = 8, t0/t1 = 16, addressing ~15 -> ~55 <= 64. acc[2][2] = 16 AGPR.
// Column space covered in 8 groups of 128 cols (4 waves x 2 tiles); work per
// thread identical to round 3. K-loop stays barrier-free, B direct from
// L2-resident ehT (contiguous 1 KB wave-segments). Epilogue logic unchanged.
__global__ __launch_bounds__(256)
__attribute__((amdgpu_waves_per_eu(4, 4)))
void mfma_fused_kernel(
    const u16* __restrict__ eh, const float* __restrict__ e2,
    const float* __restrict__ x, const float* __restrict__ emb,
    float* __restrict__ out, float* __restrict__ part) {
  __shared__ __align__(16) char smem[36992];
  u16*    sA    = (u16*)smem;              // 32 KB resident A, [ti*16+ks][lane*8]
  float*  e2s   = (float*)(smem + 32768);  // 4 KB, all 1024 e2
  int*    win   = (int*)(smem + 36864);    // 128 B winner per row
  // Epilogue aliases inside the A region (A dead after K-loop):
  u32*    cand  = (u32*)smem;              // [32][128] = 16 KB
  int*    top4k = (int*)(smem + 16384);    // [32][4]
  double* dref  = (double*)(smem + 17408); // [32][4]
  float*  q2a   = (float*)(smem + 18432);  // [32][4]
  float*  xqa   = (float*)(smem + 18944);  // [32][4]
  float*  x2a   = (float*)(smem + 19456);  // [32]

  const int tid  = threadIdx.x;
  const int wv   = tid >> 6;
  const int lane = tid & 63;
  const int lm   = lane & 15;   // fragment m/n index
  const int lq   = lane >> 4;   // fragment k-chunk (quad)
  const int m0   = blockIdx.x * 32;

  // per-wave B base in ehT (u16 units): tiles gt = ng*8 + wv*2 + tj
  // (tile = 8192 u16; wave owns 2 consecutive tiles per group)
  const u16* eB = eh + wv*16384 + lane*8;

  half8 af[2], bf[2][2];

  // BLOAD(IT): 2 contiguous 1KB wave-loads for step IT (ng=IT>>4, ks=IT&15)
#define BLOAD(IT, BF) do {                                           \
    const int ng_ = (IT) >> 4, ks_ = (IT) & 15;                      \
    const u16* pb_ = eB + ng_ * 65536 + ks_ * 512;                   \
    BF[0] = *(const half8*)(pb_);                                    \
    BF[1] = *(const half8*)(pb_ + 8192);                             \
  } while (0)

#define ALOAD(IT, AF) do {                                           \
    const u16* pa_ = sA + ((IT) & 15) * 512 + lane * 8;              \
    AF[0] = *(const half8*)(pa_);                                    \
    AF[1] = *(const half8*)(pa_ + 8192);                             \
  } while (0)

#define MM(AF, BF) do {                                              \
    _Pragma("unroll") for (int ti_ = 0; ti_ < 2; ++ti_)              \
      _Pragma("unroll") for (int tj_ = 0; tj_ < 2; ++tj_)            \
        acc[ti_][tj_] = __builtin_amdgcn_mfma_f32_16x16x32_f16(      \
            AF[ti_], BF[tj_], acc[ti_][tj_], 0, 0, 0);               \
  } while (0)

#define FOLD(NG) do {                                                \
    _Pragma("unroll") for (int tj_ = 0; tj_ < 2; ++tj_) {            \
      const int col_ = (NG)*128 + wv*32 + tj_*16 + lm;               \
      const float ek_ = e2s[col_];                                   \
      _Pragma("unroll") for (int ti_ = 0; ti_ < 2; ++ti_)            \
        _Pragma("unroll") for (int rg_ = 0; rg_ < 4; ++rg_) {        \
          const float d_ = ek_ - 2.f * acc[ti_][tj_][rg_] + 1024.f;  \
          const u32 p_ = (__float_as_uint(d_) & 0xFFFFFC00u) | (u32)col_; \
          const int s_ = ti_*4 + rg_;                                \
          if (p_ < t0[s_]) { t1[s_] = t0[s_]; t0[s_] = p_; }         \
          else if (p_ < t1[s_]) { t1[s_] = p_; }                     \
          acc[ti_][tj_][rg_] = 0.f;                                  \
        }                                                            \
    }                                                                \
  } while (0)

  // ---- prologue B prefetch: hide L2 latency under the A-stage ----
  BLOAD(0, bf[0]); BLOAD(1, bf[1]);

  // ---- stage A: fp32 x -> fp16 fragments in LDS (once per block) ----
  {
    const float* xb = x + (size_t)m0 * CD;
    const int tl = tid & 15;
    const int tc = tid >> 4;
#pragma unroll 4
    for (int i = 0; i < 16; ++i) {
      const int r  = (i & 1) * 16 + tl;
      const int c4 = tc * 8 + (i >> 1);
      const float4 v = *(const float4*)(xb + (size_t)r * CD + c4 * 4);
      const int ks  = c4 >> 3;
      const int lqw = (c4 >> 1) & 3;
      const int j   = (c4 & 1) << 2;
      const int ti  = r >> 4, lmw = r & 15;
      uint2 o;
      o.x = (u32)f2h(v.x) | ((u32)f2h(v.y) << 16);
      o.y = (u32)f2h(v.z) | ((u32)f2h(v.w) << 16);
      *(uint2*)(sA + ((ti*16 + ks) << 9) + ((lqw << 4) + lmw) * 8 + j) = o;
    }
    e2s[tid]       = e2[tid];
    e2s[tid + 256] = e2[tid + 256];
    e2s[tid + 512] = e2[tid + 512];
    e2s[tid + 768] = e2[tid + 768];
  }
  __syncthreads();   // only barrier before the epilogue

  f32x4 acc[2][2];
#pragma unroll
  for (int i = 0; i < 2; ++i)
#pragma unroll
    for (int j = 0; j < 2; ++j)
      acc[i][j] = (f32x4){0.f, 0.f, 0.f, 0.f};

  u32 t0[8], t1[8];
#pragma unroll
  for (int s = 0; s < 8; ++s) { t0[s] = 0xFFFFFFFFu; t1[s] = 0xFFFFFFFFu; }

  // ---- main K-loop: 8 col-groups (rolled) x 16 ks (unrolled), branch-free --
  // A single-buffered (ds_read, hidden by 16 waves/CU TLP); B 2-deep
  // register pipeline. Tail BLOADs (step+2 > 127) wrap harmlessly into ws
  // (max ~1.17 MB < 4 MB ws; never consumed).
#pragma unroll 1
  for (int ng = 0; ng < 8; ++ng) {
#pragma unroll
    for (int b = 0; b < 16; ++b) {
      const int it = ng * 16 + b;
      ALOAD(it, af);                       // this step's A (single buffer)
      __builtin_amdgcn_s_setprio(1);
      MM(af, bf[b & 1]);
      __builtin_amdgcn_s_setprio(0);
      BLOAD(it + 2, bf[b & 1]);            // refill just-consumed slot, 2-ahead
    }
    FOLD(ng);
  }
#undef BLOAD
#undef ALOAD
#undef MM
#undef FOLD

  __syncthreads();   // all sA/e2s reads complete before cand aliases A region
#pragma unroll
  for (int s = 0; s < 8; ++s) {
    const int ti = s >> 2, reg = s & 3;
    const int row = ti*16 + lq*4 + reg;
    uint2 pr; pr.x = t0[s]; pr.y = t1[s];
    *reinterpret_cast<uint2*>(&cand[row*128 + wv*32 + lm*2]) = pr;
  }
  __syncthreads();

  // ---- merge 128 candidates -> top-4 per row (threads 0..31) ----
  if (tid < 32) {
    u32 u0 = 0xFFFFFFFFu, u1 = 0xFFFFFFFFu, u2 = 0xFFFFFFFFu, u3 = 0xFFFFFFFFu;
    for (int i = 0; i < 128; ++i) {
      const u32 v = cand[tid*128 + ((i + tid*2) & 127)];
      if (v < u3) {
        if (v < u2) {
          u3 = u2;
          if (v < u1) {
            u2 = u1;
            if (v < u0) { u1 = u0; u0 = v; } else { u1 = v; }
          } else { u2 = v; }
        } else { u3 = v; }
      }
    }
    top4k[tid*4+0] = (int)(u0 & 1023u);
    top4k[tid*4+1] = (int)(u1 & 1023u);
    top4k[tid*4+2] = (int)(u2 & 1023u);
    top4k[tid*4+3] = (int)(u3 & 1023u);
  }
  __syncthreads();

  // ---- exact fp64 refine: thread = (row, cand), 128 threads ----
  if (tid < 128) {
    const int rr = tid >> 2, cc = tid & 3;
    const int k = top4k[rr*4 + cc];
    const float4* xr = reinterpret_cast<const float4*>(x   + (size_t)(m0+rr) * CD);
    const float4* er = reinterpret_cast<const float4*>(emb + (size_t)k * CD);
    double d0 = 0.0, d1 = 0.0;
    float q2 = 0.f, xq = 0.f, x2 = 0.f;
    for (int i = 0; i < CD/4; ++i) {
      const float4 a = xr[i], b = er[i];
      const double ta = (double)a.x - (double)b.x;
      const double tb = (double)a.y - (double)b.y;
      const double tc = (double)a.z - (double)b.z;
      const double td = (double)a.w - (double)b.w;
      d0 += ta*ta + tc*tc;
      d1 += tb*tb + td*td;
      q2 += b.x*b.x + b.y*b.y + b.z*b.z + b.w*b.w;
      xq += a.x*b.x + a.y*b.y + a.z*b.z + a.w*b.w;
      x2 += a.x*a.x + a.y*a.y + a.z*a.z + a.w*a.w;
    }
    dref[rr*4 + cc] = d0 + d1;
    q2a[rr*4 + cc] = q2;
    xqa[rr*4 + cc] = xq;
    if (cc == 0) x2a[rr] = x2;
  }
  __syncthreads();

  // ---- winner pick + idx + loss partial (wave 0; rows in lanes 0..31) ----
  if (tid < 64) {
    float s = 0.f;
    if (tid < 32) {
      double bd = dref[tid*4]; int bk = top4k[tid*4]; int bc = 0;
#pragma unroll
      for (int c = 1; c < 4; ++c) {
        const double dc = dref[tid*4 + c];
        const int kc = top4k[tid*4 + c];
        if (dc < bd || (dc == bd && kc < bk)) { bd = dc; bk = kc; bc = c; }
      }
      const int gr = m0 + tid;
      out[IOFF + gr] = (float)bk;
      win[tid] = bk;

      const float q2 = q2a[tid*4 + bc];
      const float xq = xqa[tid*4 + bc];
      const float x2 = x2a[tid];
      const float nx = fmaxf(sqrtf(x2), 1e-5f);
      const float nq = fmaxf(sqrtf(q2), 1e-5f);
      s = q2/(nq*nq) + x2/(nx*nx) - 2.f*xq/(nx*nq);
    }
    for (int off = 32; off > 0; off >>= 1) s += __shfl_down(s, off, 64);
    if (tid == 0) part[blockIdx.x] = s;
  }
  __syncthreads();

  // ---- fused gather: write this block's 32 quant rows (coalesced 1KB/instr) --
  {
    const float4* e4 = reinterpret_cast<const float4*>(emb);
    float4* ob4 = reinterpret_cast<float4*>(out + (size_t)m0 * CD);
#pragma unroll 4
    for (int i = 0; i < 16; ++i) {
      const int f = tid + (i << 8);          // 0..4095 block float4s
      const int k = win[f >> 7];             // row winner (broadcast per wave)
      ob4[f] = e4[k*128 + (f & 127)];
    }
  }
}

// ---------------- Kernel 3: reduce block partials -> both losses -------------
__global__ void loss_write_kernel(const float* __restrict__ part,
                                  float* __restrict__ out) {
  const int t = threadIdx.x;
  if (t < 16) {
    float acc = 0.f;
    for (int i = 0; i < 64; ++i) acc += part[64*t + i];
    const float v = acc * (1.f / 1048576.f);   // / (T*C)
    out[LOFF1 + t] = v;
    out[LOFF2 + t] = v;
  }
}

extern "C" void kernel_launch(void* const* d_in, const int* in_sizes, int n_in,
                              void* d_out, int out_size, void* d_ws, size_t ws_size,
                              hipStream_t stream) {
  const float* x   = (const float*)d_in[0];   // [16,2048,512] fp32
  const float* emb = (const float*)d_in[1];   // [1024,512] fp32
  float* out = (float*)d_out;

  u16*   eh   = (u16*)((char*)d_ws + WS_EH);
  float* e2   = (float*)((char*)d_ws + WS_E2);
  float* part = (float*)((char*)d_ws + WS_PART);

  conve_kernel<<<KC / 4, 256, 0, stream>>>(emb, eh, e2);
  mfma_fused_kernel<<<BT / 32, 256, 0, stream>>>(eh, e2, x, emb, out, part);
  loss_write_kernel<<<1, 64, 0, stream>>>(part, out);
}

// Round 7
// 211.276 us; speedup vs baseline: 1.3479x; 1.3479x over previous
//
#include <hip/hip_runtime.h>

typedef unsigned short u16;
typedef unsigned int u32;
typedef _Float16 half8 __attribute__((ext_vector_type(8)));
typedef float f32x4 __attribute__((ext_vector_type(4)));

// Problem constants (verified: fp32 in, fp32 out buffer of 16810016 elems)
#define BT    32768
#define CD    512
#define KC    1024
#define LOFF1 16777216
#define LOFF2 16777232
#define IOFF  16777248

// ws layout (bytes); ws >= 4 MB (probe round 4)
#define WS_EH   0          // u16 ehT[1024*512] fragment-major (1 MB)
#define WS_E2   1048576    // float e2[1024]
#define WS_PART 1052672    // float part[512]

static __device__ __forceinline__ u16 f2h(float f) {
  union { _Float16 h; u16 u; } c;
  c.h = (_Float16)f;   // RTE, identical rounding to all prior rounds
  return c.u;
}

// ---------------- Kernel 1: emb -> fp16 fragment-major ehT + exact fp32 e2 ---
// ehT layout (u16 index): ((gt*64 + ks*4 + lq)*16 + lm)*8 + j
//   gt = col>>4 (16-col tile), lm = col&15, k = ks*32 + lq*8 + j.
// A wave's B-fragment load in kernel 2 is then base + lane*16B: one
// contiguous 1 KB segment (vs row-major eh: 16 cache lines at 1 KB stride,
// 16x L2 transaction amplification -- round 1's hidden defect).
__global__ __launch_bounds__(256) void conve_kernel(const float* __restrict__ emb,
                                                    u16* __restrict__ eh,
                                                    float* __restrict__ e2) {
  const int lane = threadIdx.x & 63;
  const int r    = blockIdx.x * 4 + (threadIdx.x >> 6);
  const float4* er = reinterpret_cast<const float4*>(emb + (size_t)r * CD);
  const float4 a = er[lane*2], b = er[lane*2+1];
  uint4 o;
  o.x = (u32)f2h(a.x) | ((u32)f2h(a.y) << 16);
  o.y = (u32)f2h(a.z) | ((u32)f2h(a.w) << 16);
  o.z = (u32)f2h(b.x) | ((u32)f2h(b.y) << 16);
  o.w = (u32)f2h(b.z) | ((u32)f2h(b.w) << 16);
  // cols lane*8..+7 -> (ks = lane>>2, lq = lane&3, j = 0..7) exactly
  const int gt = r >> 4, lm = r & 15;
  const int ks = lane >> 2, lq = lane & 3;
  reinterpret_cast<uint4*>(eh)[(gt*64 + ks*4 + lq)*16 + lm] = o;
  float s = a.x*a.x + a.y*a.y + a.z*a.z + a.w*a.w
          + b.x*b.x + b.y*b.y + b.z*b.z + b.w*b.w;
  for (int off = 32; off > 0; off >>= 1) s += __shfl_down(s, off, 64);
  if (lane == 0) e2[r] = s;
}

// ---------------- Kernel 2: fused convert+MFMA+argmin+refine+gather ----------
// BYTE-EXACT round-1 structure (proven: 120 VGPR, zero spill, WRITE 65.7 MB,
// 158 us) with exactly ONE change: B-loads read the fragment-major ehT
// layout, so each of the 4 loads per PREF is one contiguous 1 KB wave
// segment instead of 16 scattered cache lines. No occupancy pin (rounds
// 4-6 proved any waves/EU pin collapses the allocator to 64 arch regs and
// spills the pipeline). Block = 64 rows, 256 threads (4 waves), 512 blocks.
__global__ __launch_bounds__(256) void mfma_fused_kernel(
    const u16* __restrict__ eh, const float* __restrict__ e2,
    const float* __restrict__ x, const float* __restrict__ emb,
    float* __restrict__ out, float* __restrict__ part) {
  __shared__ __align__(16) char smem[70144];
  u16*    sA    = (u16*)smem;              // 64 KB resident A, [ti*16+ks][lane*8]
  float*  e2s   = (float*)(smem + 65536);  // 4 KB, all 1024 e2
  int*    win   = (int*)(smem + 69632);    // 256 B winner per row
  // Epilogue aliases inside the A region (A dead after K-loop):
  u32*    cand  = (u32*)smem;              // [64][128]
  int*    top4k = (int*)(smem + 32768);    // [64][4]
  double* dref  = (double*)(smem + 33792); // [64][4]
  float*  q2a   = (float*)(smem + 35840);  // [64][4]
  float*  xqa   = (float*)(smem + 36864);  // [64][4]
  float*  x2a   = (float*)(smem + 37888);  // [64]

  const int tid  = threadIdx.x;
  const int wv   = tid >> 6;
  const int lane = tid & 63;
  const int lm   = lane & 15;   // fragment m/n index
  const int lq   = lane >> 4;   // fragment k-chunk (quad)
  const int m0   = blockIdx.x * 64;

  // per-wave B base in ehT (u16 units): tiles gt = nt*16 + wv*4 + tjl,
  // tile = 8192 u16; within tile+ks, lane offset is exactly lane*8.
  const u16* eB = eh + wv*32768 + lane*8;

  half8 afA[4], afB[4], bfA[4], bfB[4];

#define PREF(IT, AF, BF) do {                                        \
    const int nt_ = (IT) >> 4, ks_ = (IT) & 15;                      \
    const u16* pb_ = eB + nt_ * 131072 + ks_ * 512;                  \
    BF[0] = *(const half8*)(pb_);                                    \
    BF[1] = *(const half8*)(pb_ + 8192);                             \
    BF[2] = *(const half8*)(pb_ + 16384);                            \
    BF[3] = *(const half8*)(pb_ + 24576);                            \
    const u16* pa_ = sA + ks_ * 512 + lane * 8;                      \
    AF[0] = *(const half8*)(pa_);                                    \
    AF[1] = *(const half8*)(pa_ + 8192);                             \
    AF[2] = *(const half8*)(pa_ + 16384);                            \
    AF[3] = *(const half8*)(pa_ + 24576);                            \
  } while (0)

#define MM(AF, BF) do {                                              \
    _Pragma("unroll") for (int ti_ = 0; ti_ < 4; ++ti_)              \
      _Pragma("unroll") for (int tj_ = 0; tj_ < 4; ++tj_)            \
        acc[ti_][tj_] = __builtin_amdgcn_mfma_f32_16x16x32_f16(      \
            AF[ti_], BF[tj_], acc[ti_][tj_], 0, 0, 0);               \
  } while (0)

#define FOLD(NT) do {                                                \
    _Pragma("unroll") for (int tj_ = 0; tj_ < 4; ++tj_) {            \
      const int col_ = (NT)*256 + wv*64 + tj_*16 + lm;               \
      const float ek_ = e2s[col_];                                   \
      _Pragma("unroll") for (int ti_ = 0; ti_ < 4; ++ti_)            \
        _Pragma("unroll") for (int rg_ = 0; rg_ < 4; ++rg_) {        \
          const float d_ = ek_ - 2.f * acc[ti_][tj_][rg_] + 1024.f;  \
          const u32 p_ = (__float_as_uint(d_) & 0xFFFFFC00u) | (u32)col_; \
          const int s_ = ti_*4 + rg_;                                \
          if (p_ < t0[s_]) { t1[s_] = t0[s_]; t0[s_] = p_; }         \
          else if (p_ < t1[s_]) { t1[s_] = p_; }                     \
          acc[ti_][tj_][rg_] = 0.f;                                  \
        }                                                            \
    }                                                                \
  } while (0)

  // ---- prologue B prefetch: hide L2 latency under the A-stage ----
  // (PREF also reads sA, but those values are overwritten by the ALOAD side
  //  of the next PREF after the barrier before first use -- same as round 1.)

  // ---- stage A: fp32 x -> fp16 fragments in LDS (once per block) ----
  {
    const float* xb = x + (size_t)m0 * CD;
    const int tl = tid & 15;
    const int tc = tid >> 4;
#pragma unroll 8
    for (int i = 0; i < 32; ++i) {
      const int r  = (i & 3) * 16 + tl;
      const int c4 = tc * 8 + (i >> 2);
      const float4 v = *(const float4*)(xb + (size_t)r * CD + c4 * 4);
      const int ks  = c4 >> 3;
      const int lqw = (c4 >> 1) & 3;
      const int j   = (c4 & 1) << 2;
      const int ti  = r >> 4, lmw = r & 15;
      uint2 o;
      o.x = (u32)f2h(v.x) | ((u32)f2h(v.y) << 16);
      o.y = (u32)f2h(v.z) | ((u32)f2h(v.w) << 16);
      *(uint2*)(sA + ((ti*16 + ks) << 9) + ((lqw << 4) + lmw) * 8 + j) = o;
    }
    e2s[tid]       = e2[tid];
    e2s[tid + 256] = e2[tid + 256];
    e2s[tid + 512] = e2[tid + 512];
    e2s[tid + 768] = e2[tid + 768];
  }
  __syncthreads();   // only barrier before the epilogue

  f32x4 acc[4][4];
#pragma unroll
  for (int i = 0; i < 4; ++i)
#pragma unroll
    for (int j = 0; j < 4; ++j)
      acc[i][j] = (f32x4){0.f, 0.f, 0.f, 0.f};

  u32 t0[16], t1[16];
#pragma unroll
  for (int s = 0; s < 16; ++s) { t0[s] = 0xFFFFFFFFu; t1[s] = 0xFFFFFFFFu; }

  PREF(0, afA, bfA);

  // ---- main K-loop: 32 double-steps, A/B double-buffered (round-1 exact) ----
#pragma unroll 1
  for (int itp = 0; itp < 32; ++itp) {
    const int it = itp << 1;
    PREF(it + 1, afB, bfB);
    MM(afA, bfA);
    if (itp != 31) PREF(it + 2, afA, bfA);
    MM(afB, bfB);
    if ((itp & 7) == 7) FOLD(itp >> 3);   // after ks=15 of each nt
  }
#undef PREF
#undef MM
#undef FOLD

  __syncthreads();   // all sA/e2s reads complete before cand aliases A region
#pragma unroll
  for (int s = 0; s < 16; ++s) {
    const int ti = s >> 2, reg = s & 3;
    const int row = ti*16 + lq*4 + reg;
    uint2 pr; pr.x = t0[s]; pr.y = t1[s];
    *reinterpret_cast<uint2*>(&cand[row*128 + wv*32 + lm*2]) = pr;
  }
  __syncthreads();

  // ---- merge 128 candidates -> top-4 per row (threads 0..63) ----
  if (tid < 64) {
    u32 u0 = 0xFFFFFFFFu, u1 = 0xFFFFFFFFu, u2 = 0xFFFFFFFFu, u3 = 0xFFFFFFFFu;
    for (int i = 0; i < 128; ++i) {
      const u32 v = cand[tid*128 + ((i + tid*2) & 127)];
      if (v < u3) {
        if (v < u2) {
          u3 = u2;
          if (v < u1) {
            u2 = u1;
            if (v < u0) { u1 = u0; u0 = v; } else { u1 = v; }
          } else { u2 = v; }
        } else { u3 = v; }
      }
    }
    top4k[tid*4+0] = (int)(u0 & 1023u);
    top4k[tid*4+1] = (int)(u1 & 1023u);
    top4k[tid*4+2] = (int)(u2 & 1023u);
    top4k[tid*4+3] = (int)(u3 & 1023u);
  }
  __syncthreads();

  // ---- exact fp64 refine: thread = (row, cand) ----
  {
    const int rr = tid >> 2, cc = tid & 3;
    const int k = top4k[rr*4 + cc];
    const float4* xr = reinterpret_cast<const float4*>(x   + (size_t)(m0+rr) * CD);
    const float4* er = reinterpret_cast<const float4*>(emb + (size_t)k * CD);
    double d0 = 0.0, d1 = 0.0;
    float q2 = 0.f, xq = 0.f, x2 = 0.f;
    for (int i = 0; i < CD/4; ++i) {
      const float4 a = xr[i], b = er[i];
      const double ta = (double)a.x - (double)b.x;
      const double tb = (double)a.y - (double)b.y;
      const double tc = (double)a.z - (double)b.z;
      const double td = (double)a.w - (double)b.w;
      d0 += ta*ta + tc*tc;
      d1 += tb*tb + td*td;
      q2 += b.x*b.x + b.y*b.y + b.z*b.z + b.w*b.w;
      xq += a.x*b.x + a.y*b.y + a.z*b.z + a.w*b.w;
      x2 += a.x*a.x + a.y*a.y + a.z*a.z + a.w*a.w;
    }
    dref[rr*4 + cc] = d0 + d1;
    q2a[rr*4 + cc] = q2;
    xqa[rr*4 + cc] = xq;
    if (cc == 0) x2a[rr] = x2;
  }
  __syncthreads();

  // ---- winner pick + idx + loss partial (wave 0, 64 lanes = 64 rows) ----
  if (tid < 64) {
    double bd = dref[tid*4]; int bk = top4k[tid*4]; int bc = 0;
#pragma unroll
    for (int c = 1; c < 4; ++c) {
      const double dc = dref[tid*4 + c];
      const int kc = top4k[tid*4 + c];
      if (dc < bd || (dc == bd && kc < bk)) { bd = dc; bk = kc; bc = c; }
    }
    const int gr = m0 + tid;
    out[IOFF + gr] = (float)bk;
    win[tid] = bk;

    const float q2 = q2a[tid*4 + bc];
    const float xq = xqa[tid*4 + bc];
    const float x2 = x2a[tid];
    const float nx = fmaxf(sqrtf(x2), 1e-5f);
    const float nq = fmaxf(sqrtf(q2), 1e-5f);
    float s = q2/(nq*nq) + x2/(nx*nx) - 2.f*xq/(nx*nq);
    for (int off = 32; off > 0; off >>= 1) s += __shfl_down(s, off, 64);
    if (tid == 0) part[blockIdx.x] = s;
  }
  __syncthreads();

  // ---- fused gather: write this block's 64 quant rows (coalesced 1KB/instr) --
  {
    const float4* e4 = reinterpret_cast<const float4*>(emb);
    float4* ob4 = reinterpret_cast<float4*>(out + (size_t)m0 * CD);
#pragma unroll 8
    for (int i = 0; i < 32; ++i) {
      const int f = tid + (i << 8);          // 0..8191 block float4s
      const int k = win[f >> 7];             // row winner (broadcast per wave)
      ob4[f] = e4[k*128 + (f & 127)];
    }
  }
}

// ---------------- Kernel 3: reduce block partials -> both losses -------------
__global__ void loss_write_kernel(const float* __restrict__ part,
                                  float* __restrict__ out) {
  const int t = threadIdx.x;
  if (t < 16) {
    float acc = 0.f;
    for (int i = 0; i < 32; ++i) acc += part[32*t + i];
    const float v = acc * (1.f / 1048576.f);   // / (T*C)
    out[LOFF1 + t] = v;
    out[LOFF2 + t] = v;
  }
}

extern "C" void kernel_launch(void* const* d_in, const int* in_sizes, int n_in,
                              void* d_out, int out_size, void* d_ws, size_t ws_size,
                              hipStream_t stream) {
  const float* x   = (const float*)d_in[0];   // [16,2048,512] fp32
  const float* emb = (const float*)d_in[1];   // [1024,512] fp32
  float* out = (float*)d_out;

  u16*   eh   = (u16*)((char*)d_ws + WS_EH);
  float* e2   = (float*)((char*)d_ws + WS_E2);
  float* part = (float*)((char*)d_ws + WS_PART);

  conve_kernel<<<KC / 4, 256, 0, stream>>>(emb, eh, e2);
  mfma_fused_kernel<<<BT / 64, 256, 0, stream>>>(eh, e2, x, emb, out, part);
  loss_write_kernel<<<1, 64, 0, stream>>>(part, out);
}

// Round 8
// 207.899 us; speedup vs baseline: 1.3698x; 1.0162x over previous
//
#include <hip/hip_runtime.h>

typedef unsigned short u16;
typedef unsigned int u32;
typedef _Float16 half8 __attribute__((ext_vector_type(8)));
typedef float f32x4 __attribute__((ext_vector_type(4)));

// Problem constants (verified: fp32 in, fp32 out buffer of 16810016 elems)
#define BT    32768
#define CD    512
#define KC    1024
#define LOFF1 16777216
#define LOFF2 16777232
#define IOFF  16777248

// ws layout (bytes); ws >= 4 MB (probe round 4)
#define WS_EH   0          // u16 ehT[1024*512] fragment-major (1 MB)
#define WS_E2   1048576    // float e2[1024]
#define WS_PART 1052672    // float part[512]

static __device__ __forceinline__ u16 f2h(float f) {
  union { _Float16 h; u16 u; } c;
  c.h = (_Float16)f;   // RTE, identical rounding to all prior rounds
  return c.u;
}

// ---------------- Kernel 1: emb -> fp16 fragment-major ehT + exact fp32 e2 ---
// ehT layout (u16 index): ((gt*64 + ks*4 + lq)*16 + lm)*8 + j
//   gt = col>>4 (16-col tile), lm = col&15, k = ks*32 + lq*8 + j.
// A wave's B-fragment load in kernel 2 is then base + lane*16B: one
// contiguous 1 KB segment (round 7 verified: -28 us vs row-major).
__global__ __launch_bounds__(256) void conve_kernel(const float* __restrict__ emb,
                                                    u16* __restrict__ eh,
                                                    float* __restrict__ e2) {
  const int lane = threadIdx.x & 63;
  const int r    = blockIdx.x * 4 + (threadIdx.x >> 6);
  const float4* er = reinterpret_cast<const float4*>(emb + (size_t)r * CD);
  const float4 a = er[lane*2], b = er[lane*2+1];
  uint4 o;
  o.x = (u32)f2h(a.x) | ((u32)f2h(a.y) << 16);
  o.y = (u32)f2h(a.z) | ((u32)f2h(a.w) << 16);
  o.z = (u32)f2h(b.x) | ((u32)f2h(b.y) << 16);
  o.w = (u32)f2h(b.z) | ((u32)f2h(b.w) << 16);
  // cols lane*8..+7 -> (ks = lane>>2, lq = lane&3, j = 0..7) exactly
  const int gt = r >> 4, lm = r & 15;
  const int ks = lane >> 2, lq = lane & 3;
  reinterpret_cast<uint4*>(eh)[(gt*64 + ks*4 + lq)*16 + lm] = o;
  float s = a.x*a.x + a.y*a.y + a.z*a.z + a.w*a.w
          + b.x*b.x + b.y*b.y + b.z*b.z + b.w*b.w;
  for (int off = 32; off > 0; off >>= 1) s += __shfl_down(s, off, 64);
  if (lane == 0) e2[r] = s;
}

// ---------------- Kernel 2: fused convert+MFMA+argmin+refine+gather ----------
// Round-7 structure (proven clean: no spill, WRITE 65.7 MB) re-dimensioned to
// 8 waves / 512 threads per 64-row block. Same 70 KB LDS -> still 2 blocks/CU
// but 16 waves/CU = 4 waves/SIMD (was 2): doubled latency-covering TLP at
// LOWER per-wave register demand (each wave owns 2 col-tiles, not 4: bf 16
// regs, acc[4][2] 32). No waves_per_eu pin (rounds 4-6: pins collapse the
// allocator to 64 arch regs and spill). K-loop: 32 double-steps, A/B register
// double-buffer, B direct from L2-resident ehT as contiguous 1 KB segments.
// Candidate merge widens 128->256/row (superset of old survivors; identical
// comparator). fp64 refine + winner byte-identical.
__global__ __launch_bounds__(512) void mfma_fused_kernel(
    const u16* __restrict__ eh, const float* __restrict__ e2,
    const float* __restrict__ x, const float* __restrict__ emb,
    float* __restrict__ out, float* __restrict__ part) {
  __shared__ __align__(16) char smem[70144];
  u16*    sA    = (u16*)smem;              // 64 KB resident A, [ti*16+ks][lane*8]
  float*  e2s   = (float*)(smem + 65536);  // 4 KB, all 1024 e2
  int*    win   = (int*)(smem + 69632);    // 256 B winner per row
  // Epilogue aliases (A/e2s dead after K-loop+FOLD):
  u32*    cand  = (u32*)smem;              // [64][256] = 64 KB (= sA region)
  int*    top4k = (int*)(smem + 65536);    // [64][4] = 1 KB (= e2s region)
  double* dref  = (double*)smem;           // [64][4] = 2 KB (cand dead by then)
  float*  q2a   = (float*)(smem + 2048);   // [64][4]
  float*  xqa   = (float*)(smem + 3072);   // [64][4]
  float*  x2a   = (float*)(smem + 4096);   // [64]

  const int tid  = threadIdx.x;
  const int wv   = tid >> 6;    // 0..7
  const int lane = tid & 63;
  const int lm   = lane & 15;   // fragment m/n index
  const int lq   = lane >> 4;   // fragment k-chunk (quad)
  const int m0   = blockIdx.x * 64;

  // per-wave B base in ehT (u16 units): tiles gt = nt*16 + wv*2 + tj,
  // tile = 8192 u16; within tile+ks, lane offset is exactly lane*8.
  const u16* eB = eh + wv*16384 + lane*8;

  half8 afA[4], afB[4], bfA[2], bfB[2];

#define PREF(IT, AF, BF) do {                                        \
    const int nt_ = (IT) >> 4, ks_ = (IT) & 15;                      \
    const u16* pb_ = eB + nt_ * 131072 + ks_ * 512;                  \
    BF[0] = *(const half8*)(pb_);                                    \
    BF[1] = *(const half8*)(pb_ + 8192);                             \
    const u16* pa_ = sA + ks_ * 512 + lane * 8;                      \
    AF[0] = *(const half8*)(pa_);                                    \
    AF[1] = *(const half8*)(pa_ + 8192);                             \
    AF[2] = *(const half8*)(pa_ + 16384);                            \
    AF[3] = *(const half8*)(pa_ + 24576);                            \
  } while (0)

#define MM(AF, BF) do {                                              \
    _Pragma("unroll") for (int ti_ = 0; ti_ < 4; ++ti_)              \
      _Pragma("unroll") for (int tj_ = 0; tj_ < 2; ++tj_)            \
        acc[ti_][tj_] = __builtin_amdgcn_mfma_f32_16x16x32_f16(      \
            AF[ti_], BF[tj_], acc[ti_][tj_], 0, 0, 0);               \
  } while (0)

#define FOLD(NT) do {                                                \
    _Pragma("unroll") for (int tj_ = 0; tj_ < 2; ++tj_) {            \
      const int col_ = (NT)*256 + wv*32 + tj_*16 + lm;               \
      const float ek_ = e2s[col_];                                   \
      _Pragma("unroll") for (int ti_ = 0; ti_ < 4; ++ti_)            \
        _Pragma("unroll") for (int rg_ = 0; rg_ < 4; ++rg_) {        \
          const float d_ = ek_ - 2.f * acc[ti_][tj_][rg_] + 1024.f;  \
          const u32 p_ = (__float_as_uint(d_) & 0xFFFFFC00u) | (u32)col_; \
          const int s_ = ti_*4 + rg_;                                \
          if (p_ < t0[s_]) { t1[s_] = t0[s_]; t0[s_] = p_; }         \
          else if (p_ < t1[s_]) { t1[s_] = p_; }                     \
          acc[ti_][tj_][rg_] = 0.f;                                  \
        }                                                            \
    }                                                                \
  } while (0)

  // ---- stage A: fp32 x -> fp16 fragments in LDS (once per block) ----
  // 512 threads x 16 float4s cover the 64x512 panel exactly once.
  {
    const float* xb = x + (size_t)m0 * CD;
    const int tl = tid & 15;
    const int tc = tid >> 4;          // 0..31
#pragma unroll 4
    for (int i = 0; i < 16; ++i) {
      const int r  = (i & 3) * 16 + tl;
      const int c4 = tc * 4 + (i >> 2);   // 0..127
      const float4 v = *(const float4*)(xb + (size_t)r * CD + c4 * 4);
      const int ks  = c4 >> 3;
      const int lqw = (c4 >> 1) & 3;
      const int j   = (c4 & 1) << 2;
      const int ti  = r >> 4, lmw = r & 15;
      uint2 o;
      o.x = (u32)f2h(v.x) | ((u32)f2h(v.y) << 16);
      o.y = (u32)f2h(v.z) | ((u32)f2h(v.w) << 16);
      *(uint2*)(sA + ((ti*16 + ks) << 9) + ((lqw << 4) + lmw) * 8 + j) = o;
    }
    e2s[tid]       = e2[tid];
    e2s[tid + 512] = e2[tid + 512];
  }
  __syncthreads();   // only barrier before the epilogue

  f32x4 acc[4][2];
#pragma unroll
  for (int i = 0; i < 4; ++i)
#pragma unroll
    for (int j = 0; j < 2; ++j)
      acc[i][j] = (f32x4){0.f, 0.f, 0.f, 0.f};

  u32 t0[16], t1[16];
#pragma unroll
  for (int s = 0; s < 16; ++s) { t0[s] = 0xFFFFFFFFu; t1[s] = 0xFFFFFFFFu; }

  PREF(0, afA, bfA);

  // ---- main K-loop: 32 double-steps, A/B double-buffered, branch-light ----
#pragma unroll 1
  for (int itp = 0; itp < 32; ++itp) {
    const int it = itp << 1;
    PREF(it + 1, afB, bfB);
    MM(afA, bfA);
    if (itp != 31) PREF(it + 2, afA, bfA);
    MM(afB, bfB);
    if ((itp & 7) == 7) FOLD(itp >> 3);   // after ks=15 of each nt
  }
#undef PREF
#undef MM
#undef FOLD

  __syncthreads();   // all sA/e2s reads complete before cand aliases A region
#pragma unroll
  for (int s = 0; s < 16; ++s) {
    const int ti = s >> 2, reg = s & 3;
    const int row = ti*16 + lq*4 + reg;
    uint2 pr; pr.x = t0[s]; pr.y = t1[s];
    *reinterpret_cast<uint2*>(&cand[row*256 + wv*32 + lm*2]) = pr;
  }
  __syncthreads();

  // ---- merge 256 candidates -> top-4 per row (threads 0..63) ----
  if (tid < 64) {
    u32 u0 = 0xFFFFFFFFu, u1 = 0xFFFFFFFFu, u2 = 0xFFFFFFFFu, u3 = 0xFFFFFFFFu;
    for (int i = 0; i < 256; ++i) {
      const u32 v = cand[tid*256 + ((i + tid*4) & 255)];
      if (v < u3) {
        if (v < u2) {
          u3 = u2;
          if (v < u1) {
            u2 = u1;
            if (v < u0) { u1 = u0; u0 = v; } else { u1 = v; }
          } else { u2 = v; }
        } else { u3 = v; }
      }
    }
    top4k[tid*4+0] = (int)(u0 & 1023u);
    top4k[tid*4+1] = (int)(u1 & 1023u);
    top4k[tid*4+2] = (int)(u2 & 1023u);
    top4k[tid*4+3] = (int)(u3 & 1023u);
  }
  __syncthreads();

  // ---- exact fp64 refine: thread = (row, cand), 256 threads ----
  if (tid < 256) {
    const int rr = tid >> 2, cc = tid & 3;
    const int k = top4k[rr*4 + cc];
    const float4* xr = reinterpret_cast<const float4*>(x   + (size_t)(m0+rr) * CD);
    const float4* er = reinterpret_cast<const float4*>(emb + (size_t)k * CD);
    double d0 = 0.0, d1 = 0.0;
    float q2 = 0.f, xq = 0.f, x2 = 0.f;
    for (int i = 0; i < CD/4; ++i) {
      const float4 a = xr[i], b = er[i];
      const double ta = (double)a.x - (double)b.x;
      const double tb = (double)a.y - (double)b.y;
      const double tc = (double)a.z - (double)b.z;
      const double td = (double)a.w - (double)b.w;
      d0 += ta*ta + tc*tc;
      d1 += tb*tb + td*td;
      q2 += b.x*b.x + b.y*b.y + b.z*b.z + b.w*b.w;
      xq += a.x*b.x + a.y*b.y + a.z*b.z + a.w*b.w;
      x2 += a.x*a.x + a.y*a.y + a.z*a.z + a.w*a.w;
    }
    dref[rr*4 + cc] = d0 + d1;
    q2a[rr*4 + cc] = q2;
    xqa[rr*4 + cc] = xq;
    if (cc == 0) x2a[rr] = x2;
  }
  __syncthreads();

  // ---- winner pick + idx + loss partial (wave 0, 64 lanes = 64 rows) ----
  if (tid < 64) {
    double bd = dref[tid*4]; int bk = top4k[tid*4]; int bc = 0;
#pragma unroll
    for (int c = 1; c < 4; ++c) {
      const double dc = dref[tid*4 + c];
      const int kc = top4k[tid*4 + c];
      if (dc < bd || (dc == bd && kc < bk)) { bd = dc; bk = kc; bc = c; }
    }
    const int gr = m0 + tid;
    out[IOFF + gr] = (float)bk;
    win[tid] = bk;

    const float q2 = q2a[tid*4 + bc];
    const float xq = xqa[tid*4 + bc];
    const float x2 = x2a[tid];
    const float nx = fmaxf(sqrtf(x2), 1e-5f);
    const float nq = fmaxf(sqrtf(q2), 1e-5f);
    float s = q2/(nq*nq) + x2/(nx*nx) - 2.f*xq/(nx*nq);
    for (int off = 32; off > 0; off >>= 1) s += __shfl_down(s, off, 64);
    if (tid == 0) part[blockIdx.x] = s;
  }
  __syncthreads();

  // ---- fused gather: write this block's 64 quant rows (coalesced 2KB/instr) --
  {
    const float4* e4 = reinterpret_cast<const float4*>(emb);
    float4* ob4 = reinterpret_cast<float4*>(out + (size_t)m0 * CD);
#pragma unroll 4
    for (int i = 0; i < 16; ++i) {
      const int f = tid + (i << 9);          // 0..8191 block float4s
      const int k = win[f >> 7];             // row winner (broadcast per wave)
      ob4[f] = e4[k*128 + (f & 127)];
    }
  }
}

// ---------------- Kernel 3: reduce block partials -> both losses -------------
__global__ void loss_write_kernel(const float* __restrict__ part,
                                  float* __restrict__ out) {
  const int t = threadIdx.x;
  if (t < 16) {
    float acc = 0.f;
    for (int i = 0; i < 32; ++i) acc += part[32*t + i];
    const float v = acc * (1.f / 1048576.f);   // / (T*C)
    out[LOFF1 + t] = v;
    out[LOFF2 + t] = v;
  }
}

extern "C" void kernel_launch(void* const* d_in, const int* in_sizes, int n_in,
                              void* d_out, int out_size, void* d_ws, size_t ws_size,
                              hipStream_t stream) {
  const float* x   = (const float*)d_in[0];   // [16,2048,512] fp32
  const float* emb = (const float*)d_in[1];   // [1024,512] fp32
  float* out = (float*)d_out;

  u16*   eh   = (u16*)((char*)d_ws + WS_EH);
  float* e2   = (float*)((char*)d_ws + WS_E2);
  float* part = (float*)((char*)d_ws + WS_PART);

  conve_kernel<<<KC / 4, 256, 0, stream>>>(emb, eh, e2);
  mfma_fused_kernel<<<BT / 64, 512, 0, stream>>>(eh, e2, x, emb, out, part);
  loss_write_kernel<<<1, 64, 0, stream>>>(part, out);
}